// Round 8
// baseline (404.692 us; speedup 1.0000x reference)
//
#include <hip/hip_runtime.h>
#include <stdint.h>

#define D 128
#define Ssz 10
#define HP 136   // LDS row pad (u16) — 272 B row stride, 16B-aligned (mult of 8!)
#define NB 4096  // batch
#define KSLICE 512

typedef uint16_t u16;
typedef uint32_t u32;
typedef __attribute__((ext_vector_type(8))) short short8;
typedef __attribute__((ext_vector_type(4))) float f32x4;

__device__ __forceinline__ u16 f2bf(float f){
  u32 x = __float_as_uint(f);
  return (u16)((x + 0x7fffu + ((x >> 16) & 1u)) >> 16);   // RNE
}
__device__ __forceinline__ float bf2f(u16 u){ return __uint_as_float(((u32)u) << 16); }

// branch-free fast tanh: 1 - 2/(e^{2x}+1); exact at +-inf, abs err ~1e-7
__device__ __forceinline__ float ftanh(float x){
  float e = __expf(2.0f * x);
  return 1.0f - 2.0f / (e + 1.0f);
}

// Fused preamble: all weight transposes + cell cvt in one launch.
__global__ __launch_bounds__(256) void prep_kernel(
    const float* __restrict__ W_drug, const float* __restrict__ W_gene,
    const float* __restrict__ rnn_Wx, const float* __restrict__ rnn_Wh,
    const float* __restrict__ cell_tab,
    u16* __restrict__ WdT, u16* __restrict__ WgT,
    u16* __restrict__ WxT6, u16* __restrict__ WhT6,
    u16* __restrict__ cellT)
{
  int i = blockIdx.x * 256 + threadIdx.x;
  if (i < 131072){
    int n = i >> 10, k = i & 1023;
    WdT[i] = f2bf(W_drug[k * D + n]);
  } else if (i < 393216){
    int j = i - 131072;
    int n = j >> 11, k = j & 2047;
    WgT[j] = f2bf(W_gene[k * D + n]);
  } else if (i < 491520){
    int j = i - 393216;
    int n = (j >> 7) & 127, k = j & 127;
    WxT6[j] = f2bf(rnn_Wx[(j & ~16383) + k * D + n]);
  } else if (i < 589824){
    int j = i - 491520;
    int n = (j >> 7) & 127, k = j & 127;
    WhT6[j] = f2bf(rnn_Wh[(j & ~16383) + k * D + n]);
  } else {
    int j = i - 589824;                 // j < 128000
    float v0 = cell_tab[2 * j], v1 = cell_tab[2 * j + 1];
    ((u32*)cellT)[j] = (u32)f2bf(v0) | ((u32)f2bf(v1) << 16);
  }
}

// Split-K partial projection — NO LDS, NO barriers. grid (M/64, K/KSLICE).
// 4 independent waves/block, each: 16 rows x 128 cols over a 512-wide K-slice.
// B fragments read DIRECT from L2-resident WT (xw_cell-proven pattern);
// A double-buffered in registers. Waves free-run -> latency hidden by TLP
// (the barrier-chunk structure was stuck at 105-121us / 4% MfmaUtil).
__global__ __launch_bounds__(256) void proj_part(
    const float* __restrict__ feats, int K, int M, int Mpad,
    const u16* __restrict__ WT,       // bf16 [128][K]
    const float* __restrict__ bias,   // f32 [128]
    float* __restrict__ pbuf)         // f32 [ksplit][Mpad][128]
{
  int lane = threadIdx.x & 63, wave = threadIdx.x >> 6;
  int quad = lane >> 4, l16 = lane & 15;
  int m0 = blockIdx.x * 64 + wave * 16;
  int kz = blockIdx.y;
  long kb = (long)kz * KSLICE;

  int row = min(m0 + l16, M - 1);
  const float* aptr = feats + (long)row * K + kb + quad * 8;

  f32x4 acc[8];
#pragma unroll
  for (int nt = 0; nt < 8; ++nt){
    float bv = (kz == 0) ? bias[nt * 16 + l16] : 0.f;
    f32x4 t = {bv, bv, bv, bv};
    acc[nt] = t;
  }

  f32x4 afA[4][2], afB[4][2];
  auto loadA = [&](f32x4 (&af)[4][2], int kc){
#pragma unroll
    for (int ks = 0; ks < 4; ++ks){
      af[ks][0] = *(const f32x4*)(aptr + kc + ks * 32);
      af[ks][1] = *(const f32x4*)(aptr + kc + ks * 32 + 4);
    }
  };
  auto compute = [&](f32x4 (&af)[4][2], int kc){
    short8 a[4];
#pragma unroll
    for (int ks = 0; ks < 4; ++ks)
#pragma unroll
      for (int q = 0; q < 4; ++q){
        a[ks][q]     = (short)f2bf(af[ks][0][q]);
        a[ks][4 + q] = (short)f2bf(af[ks][1][q]);
      }
#pragma unroll
    for (int nt = 0; nt < 8; ++nt){
      const u16* wp = WT + (long)(nt * 16 + l16) * K + kb + kc + quad * 8;
      short8 b0 = *(const short8*)(wp);
      short8 b1 = *(const short8*)(wp + 32);
      short8 b2 = *(const short8*)(wp + 64);
      short8 b3 = *(const short8*)(wp + 96);
      acc[nt] = __builtin_amdgcn_mfma_f32_16x16x32_bf16(a[0], b0, acc[nt], 0, 0, 0);
      acc[nt] = __builtin_amdgcn_mfma_f32_16x16x32_bf16(a[1], b1, acc[nt], 0, 0, 0);
      acc[nt] = __builtin_amdgcn_mfma_f32_16x16x32_bf16(a[2], b2, acc[nt], 0, 0, 0);
      acc[nt] = __builtin_amdgcn_mfma_f32_16x16x32_bf16(a[3], b3, acc[nt], 0, 0, 0);
    }
  };

  loadA(afA, 0);
  loadA(afB, 128);
  compute(afA, 0);
  loadA(afA, 256);
  compute(afB, 128);
  loadA(afB, 384);
  compute(afA, 256);
  compute(afB, 384);

  // store partials (padded rows always valid in pbuf)
  float* pb = pbuf + ((long)kz * Mpad + m0) * D;
#pragma unroll
  for (int nt = 0; nt < 8; ++nt){
    int col = nt * 16 + l16;
#pragma unroll
    for (int r = 0; r < 4; ++r)
      pb[(long)(quad * 4 + r) * D + col] = acc[nt][r];
  }
}

// Reduce split-K partials + per-layer x@Wx epilogue for ALL three tables.
// grid 408: bx<32 cell (bf16 table direct), <95 drug (reduce 2 + drugPf), else
// gene (reduce 4). One wave = 16 rows, full 128 cols.
__global__ __launch_bounds__(256) void proj_fin(
    const u16* __restrict__ cellT,     // bf16 [2000][128]
    const float* __restrict__ pbuf_d,  // f32 [2][4032][128]
    const float* __restrict__ pbuf_g,  // f32 [4][20032][128]
    const u16* __restrict__ WxT6,      // bf16 [6][128][128]
    const float* __restrict__ bvec,    // f32 [6][128] (rnn_b)
    float* __restrict__ xwb,           // f32 [2][26000][128]
    float* __restrict__ drugPf)        // f32 [4000][128]
{
  int bx = blockIdx.x;
  int lane = threadIdx.x & 63, wave = threadIdx.x >> 6;
  int quad = lane >> 4, l16 = lane & 15;

  int t, m0, M, rbase;
  if (bx < 32)      { t = 0; m0 = bx * 64;        M = 2000;  rbase = 0;    }
  else if (bx < 95) { t = 1; m0 = (bx - 32) * 64; M = 4000;  rbase = 2000; }
  else              { t = 2; m0 = (bx - 95) * 64; M = 20000; rbase = 6000; }
  int mt = m0 + wave * 16;

  short8 a[4];
  if (t == 0){
    int mr = min(mt + l16, 1999);
#pragma unroll
    for (int ks = 0; ks < 4; ++ks)
      a[ks] = *(const short8*)(cellT + (long)mr * D + ks * 32 + quad * 8);
  } else if (t == 1){
    long r0 = (long)(mt + l16) * D;
    const long st = (long)4032 * D;
#pragma unroll
    for (int ks = 0; ks < 4; ++ks){
      long off = r0 + ks * 32 + quad * 8;
      f32x4 s0 = *(const f32x4*)(pbuf_d + off) + *(const f32x4*)(pbuf_d + st + off);
      f32x4 s1 = *(const f32x4*)(pbuf_d + off + 4) + *(const f32x4*)(pbuf_d + st + off + 4);
#pragma unroll
      for (int q = 0; q < 4; ++q){
        a[ks][q]     = (short)f2bf(s0[q]);
        a[ks][4 + q] = (short)f2bf(s1[q]);
      }
      if (mt + l16 < 4000){
        *(f32x4*)(drugPf + off)     = s0;
        *(f32x4*)(drugPf + off + 4) = s1;
      }
    }
  } else {
    long r0 = (long)(mt + l16) * D;
    const long st = (long)20032 * D;
#pragma unroll
    for (int ks = 0; ks < 4; ++ks){
      long off = r0 + ks * 32 + quad * 8;
      f32x4 s0 = *(const f32x4*)(pbuf_g + off) + *(const f32x4*)(pbuf_g + st + off)
               + *(const f32x4*)(pbuf_g + 2 * st + off) + *(const f32x4*)(pbuf_g + 3 * st + off);
      f32x4 s1 = *(const f32x4*)(pbuf_g + off + 4) + *(const f32x4*)(pbuf_g + st + off + 4)
               + *(const f32x4*)(pbuf_g + 2 * st + off + 4) + *(const f32x4*)(pbuf_g + 3 * st + off + 4);
#pragma unroll
      for (int q = 0; q < 4; ++q){
        a[ks][q]     = (short)f2bf(s0[q]);
        a[ks][4 + q] = (short)f2bf(s1[q]);
      }
    }
  }

  auto xw_pass = [&](const u16* Wx, const float* rb, float* xw){
    f32x4 ac2[8];
#pragma unroll
    for (int nt = 0; nt < 8; ++nt){
      float bv = rb[nt * 16 + l16];
      f32x4 tv = {bv, bv, bv, bv};
      ac2[nt] = tv;
    }
#pragma unroll
    for (int nt = 0; nt < 8; ++nt){
      const u16* wp = Wx + (long)(nt * 16 + l16) * D + quad * 8;
      short8 b0 = *(const short8*)(wp);
      short8 b1 = *(const short8*)(wp + 32);
      short8 b2 = *(const short8*)(wp + 64);
      short8 b3 = *(const short8*)(wp + 96);
      ac2[nt] = __builtin_amdgcn_mfma_f32_16x16x32_bf16(a[0], b0, ac2[nt], 0, 0, 0);
      ac2[nt] = __builtin_amdgcn_mfma_f32_16x16x32_bf16(a[1], b1, ac2[nt], 0, 0, 0);
      ac2[nt] = __builtin_amdgcn_mfma_f32_16x16x32_bf16(a[2], b2, ac2[nt], 0, 0, 0);
      ac2[nt] = __builtin_amdgcn_mfma_f32_16x16x32_bf16(a[3], b3, ac2[nt], 0, 0, 0);
    }
#pragma unroll
    for (int nt = 0; nt < 8; ++nt){
      int col = nt * 16 + l16;
#pragma unroll
      for (int r = 0; r < 4; ++r){
        int mrow = mt + quad * 4 + r;
        if (mrow < M) xw[(long)mrow * D + col] = ac2[nt][r];
      }
    }
  };
  xw_pass(WxT6 + (size_t)t * 16384,       bvec + (size_t)t * D,
          xwb + (size_t)rbase * D);
  xw_pass(WxT6 + (size_t)(3 + t) * 16384, bvec + (size_t)(3 + t) * D,
          xwb + (size_t)(26000 + rbase) * D);
}

// Fused 6-way RNN (3 types x 2 layers): grid = (256, 3, 2), block 256 = 4 waves.
// h = tanh(xw_gathered + h @ Wh). Proven structure + 2-deep gather prefetch
// (triple-buffered xw/nid, compile-time rotation — ~2 steps of latency slack).
__global__ __launch_bounds__(256, 3) void rnn6_kernel(
    const float* __restrict__ xwb,   // f32 [2][26000][128]
    const u16* __restrict__ WhT6,    // bf16 [6][128][128]
    const int* __restrict__ cn, const int* __restrict__ dn,
    const int* __restrict__ gn,      // [2][4096][10]
    u16* __restrict__ agg)           // bf16 [2][3][4096][128]
{
  __shared__ u16 hbuf[16 * HP];

  int t = blockIdx.y, l = blockIdx.z;
  const int* idx = (t == 0) ? cn : (t == 1) ? dn : gn;
  int rbase = (t == 0) ? 0 : (t == 1) ? 2000 : 6000;
  int nmax  = (t == 0) ? 2000 : (t == 1) ? 4000 : 20000;
  const float* xw = xwb + ((size_t)l * 26000 + rbase) * D;
  const u16* WT = WhT6 + (size_t)(l * 3 + t) * 16384;

  int tid = threadIdx.x, lane = tid & 63, wave = tid >> 6;
  int quad = lane >> 4, l16 = lane & 15;
  int n0 = wave * 32;

  short8 whf[2][4];
#pragma unroll
  for (int nt = 0; nt < 2; ++nt){
    int n = n0 + nt * 16 + l16;
#pragma unroll
    for (int ks = 0; ks < 4; ++ks)
      whf[nt][ks] = *(const short8*)(WT + n * D + ks * 32 + quad * 8);
  }

  for (int i = tid; i < 16 * HP; i += 256) hbuf[i] = 0;   // h0 = zeros

  int brow = blockIdx.x * 16;
  const int* ip = idx + ((size_t)l * NB + brow + quad * 4) * Ssz;
  long arow = ((long)(l * 3 + t) * NB + brow) * D;

  int n0b[4], n1b[4], n2b[4];
  float x0b[8], x1b[8], x2b[8];
  auto ldnid = [&](int (&nb)[4], int s){
#pragma unroll
    for (int r = 0; r < 4; ++r) nb[r] = min(max(ip[r * Ssz + s], 0), nmax - 1);
  };
  auto gather = [&](float (&xb)[8], int (&nb)[4]){
#pragma unroll
    for (int r = 0; r < 4; ++r){
      const float* p = xw + (long)nb[r] * D + n0 + l16;
      xb[r] = p[0]; xb[4 + r] = p[16];
    }
  };
  ldnid(n0b, 0); ldnid(n1b, 1); ldnid(n2b, 2);
  gather(x0b, n0b);
  gather(x1b, n1b);
  __syncthreads();   // hbuf zeros visible

  auto step = [&](int s, float (&xwc)[8], float (&xwg)[8],
                  int (&nidg)[4], int (&nidl)[4]){
    if (s + 2 < Ssz) gather(xwg, nidg);     // xw(s+2), 2 steps of slack
    if (s + 3 < Ssz) ldnid(nidl, s + 3);
    short8 hf[4];
#pragma unroll
    for (int ks = 0; ks < 4; ++ks)
      hf[ks] = *(const short8*)(&hbuf[l16 * HP + ks * 32 + quad * 8]);
    f32x4 acc0 = {xwc[0], xwc[1], xwc[2], xwc[3]};
    f32x4 acc1 = {xwc[4], xwc[5], xwc[6], xwc[7]};
#pragma unroll
    for (int ks = 0; ks < 4; ++ks){
      acc0 = __builtin_amdgcn_mfma_f32_16x16x32_bf16(hf[ks], whf[0][ks], acc0, 0, 0, 0);
      acc1 = __builtin_amdgcn_mfma_f32_16x16x32_bf16(hf[ks], whf[1][ks], acc1, 0, 0, 0);
    }
    __syncthreads();   // all waves done READING old h
#pragma unroll
    for (int r = 0; r < 4; ++r){
      float v0 = ftanh(acc0[r]);
      float v1 = ftanh(acc1[r]);
      hbuf[(quad * 4 + r) * HP + n0 + l16]      = f2bf(v0);
      hbuf[(quad * 4 + r) * HP + n0 + 16 + l16] = f2bf(v1);
      if (s == Ssz - 1){
        long o = arow + (long)(quad * 4 + r) * D;
        agg[o + n0 + l16]      = f2bf(v0);
        agg[o + n0 + 16 + l16] = f2bf(v1);
      }
    }
    __syncthreads();   // new h visible
  };

  // xw(s) lives in x[s%3]; gather target (s+2)%3; nid(s+3) -> slot s%3
  step(0, x0b, x2b, n2b, n0b);
  step(1, x1b, x0b, n0b, n1b);
  step(2, x2b, x1b, n1b, n2b);
  step(3, x0b, x2b, n2b, n0b);
  step(4, x1b, x0b, n0b, n1b);
  step(5, x2b, x1b, n1b, n2b);
  step(6, x0b, x2b, n2b, n0b);
  step(7, x1b, x0b, n0b, n1b);
  step(8, x2b, x1b, n1b, n2b);
  step(9, x0b, x2b, n2b, n0b);
}

// Fused: h0 gather + both attention layers; h stays in registers between layers.
__global__ __launch_bounds__(256) void att2_kernel(
    const float* __restrict__ drugPf,  // f32 [4000][128]
    const int* __restrict__ center_ids,
    const u16* __restrict__ agg,       // bf16 [2][3][4096][128]
    const float* __restrict__ att_w,   // f32 [2][256]
    float* __restrict__ out)           // f32 [4096][128]
{
  int gt = blockIdx.x * 256 + threadIdx.x;
  int lane = gt & 63;
  int b = gt >> 6;
  int e = 2 * lane;

  int row = min(max(center_ids[b], 0), 3999);
  float h0 = drugPf[(long)row * D + e];
  float h1 = drugPf[(long)row * D + e + 1];

#pragma unroll
  for (int l = 0; l < 2; ++l){
    float c[4][2];
    c[0][0] = h0; c[0][1] = h1;
#pragma unroll
    for (int t = 0; t < 3; ++t){
      long o = ((long)(l * 3 + t) * NB + b) * D + e;
      c[t + 1][0] = bf2f(agg[o]);
      c[t + 1][1] = bf2f(agg[o + 1]);
    }
    const float* aw = att_w + l * 2 * D;
    float as0 = aw[e],     as1 = aw[e + 1];
    float ac0 = aw[D + e], ac1 = aw[D + e + 1];

    float selfp = c[0][0] * as0 + c[0][1] * as1;
    float sc[4];
#pragma unroll
    for (int cc = 0; cc < 4; ++cc) sc[cc] = selfp + c[cc][0] * ac0 + c[cc][1] * ac1;
#pragma unroll
    for (int off = 32; off >= 1; off >>= 1){
#pragma unroll
      for (int cc = 0; cc < 4; ++cc) sc[cc] += __shfl_xor(sc[cc], off, 64);
    }
#pragma unroll
    for (int cc = 0; cc < 4; ++cc) sc[cc] = sc[cc] > 0.f ? sc[cc] : 0.01f * sc[cc];

    float mx = fmaxf(fmaxf(sc[0], sc[1]), fmaxf(sc[2], sc[3]));
    float ex[4], ssum = 0.f;
#pragma unroll
    for (int cc = 0; cc < 4; ++cc){ ex[cc] = expf(sc[cc] - mx); ssum += ex[cc]; }
    float o0 = 0.f, o1 = 0.f;
#pragma unroll
    for (int cc = 0; cc < 4; ++cc){
      float aa = ex[cc] / ssum;
      o0 += aa * c[cc][0];
      o1 += aa * c[cc][1];
    }
    h0 = o0; h1 = o1;
  }
  out[(long)b * D + e]     = h0;
  out[(long)b * D + e + 1] = h1;
}

extern "C" void kernel_launch(void* const* d_in, const int* in_sizes, int n_in,
                              void* d_out, int out_size, void* d_ws, size_t ws_size,
                              hipStream_t stream)
{
  const float* drug_feats = (const float*)d_in[0];   // [4000][1024]
  const float* gene_feats = (const float*)d_in[1];   // [20000][2048]
  const float* cell_tab   = (const float*)d_in[2];   // [2000][128]
  const float* W_drug     = (const float*)d_in[3];   // [1024][128]
  const float* b_drug     = (const float*)d_in[4];   // [128]
  const float* W_gene     = (const float*)d_in[5];   // [2048][128]
  const float* b_gene     = (const float*)d_in[6];   // [128]
  const float* rnn_Wx     = (const float*)d_in[7];   // [2][3][128][128]
  const float* rnn_Wh     = (const float*)d_in[8];
  const float* rnn_b      = (const float*)d_in[9];   // [2][3][128]
  const float* att_w      = (const float*)d_in[10];  // [2][256]
  const int* center_ids   = (const int*)d_in[11];    // [4096]
  const int* cell_neigh   = (const int*)d_in[12];    // [2][4096][10]
  const int* drug_neigh   = (const int*)d_in[13];
  const int* gene_neigh   = (const int*)d_in[14];

  // ws layout:
  //  u16: WdT 131072 | WgT 262144 | WxT6 98304 | WhT6 98304 | cellT 256000
  //  f32: drugPf 512000 | xwb 6656000
  //  u16: agg 3145728
  //  f32: pbuf_g 4*20032*128 | pbuf_d 2*4032*128         (total ~82 MB)
  u16* ws     = (u16*)d_ws;
  u16* WdT    = ws;
  u16* WgT    = WdT + 131072;
  u16* WxT6   = WgT + 262144;
  u16* WhT6   = WxT6 + 98304;
  u16* cellT  = WhT6 + 98304;
  float* drugPf = (float*)(cellT + 256000);
  float* xwb    = drugPf + 512000;
  u16* agg      = (u16*)(xwb + 6656000);
  float* pbuf_g = (float*)(agg + 3145728);
  float* pbuf_d = pbuf_g + (size_t)4 * 20032 * 128;

  float* h = (float*)d_out;               // f32 [4096][128]

  // 1. preamble
  prep_kernel<<<2804, 256, 0, stream>>>(W_drug, W_gene, rnn_Wx, rnn_Wh, cell_tab,
                                        WdT, WgT, WxT6, WhT6, cellT);

  // 2+3. split-K barrier-free partial projections
  proj_part<<<dim3(313, 4), 256, 0, stream>>>(gene_feats, 2048, 20000, 20032,
                                              WgT, b_gene, pbuf_g);
  proj_part<<<dim3(63, 2), 256, 0, stream>>>(drug_feats, 1024, 4000, 4032,
                                             WdT, b_drug, pbuf_d);

  // 4. reduce + x@Wx epilogue for cell/drug/gene (both layers)
  proj_fin<<<408, 256, 0, stream>>>(cellT, pbuf_d, pbuf_g, WxT6, rnn_b,
                                    xwb, drugPf);

  // 5. all 6 (layer,type) RNN aggregations
  rnn6_kernel<<<dim3(NB / 16, 3, 2), 256, 0, stream>>>(
      xwb, WhT6, cell_neigh, drug_neigh, gene_neigh, agg);

  // 6. h0 gather + both attention layers
  att2_kernel<<<NB / 4, 256, 0, stream>>>(drugPf, center_ids, agg, att_w, h);
}